// Round 12
// baseline (347.748 us; speedup 1.0000x reference)
//
#include <hip/hip_runtime.h>
#include <math.h>
#include <stdint.h>

#define NPTS   524288
#define TSZ    524288u
#define HMASK  (TSZ - 1u)
#define PRIME1 2654435761u
#define PRIME2 805459861u
#define NLVL   24
#define NBKT   32768

typedef float    v4f __attribute__((ext_vector_type(4)));
typedef _Float16 v4h __attribute__((ext_vector_type(4)));

#define MFMA16(A,B,C) __builtin_amdgcn_mfma_f32_16x16x16f16((A),(B),(C),0,0,0)

struct ResParams { float r[NLVL]; };

__device__ __forceinline__ uint32_t pack_f16x2(float a, float b) {
    union { _Float16 h[2]; uint32_t u; } c;
    c.h[0] = (_Float16)a; c.h[1] = (_Float16)b;
    return c.u;
}

__device__ __forceinline__ float softplus_f(float x) {
    return fmaxf(x, 0.f) + log1pf(expf(-fabsf(x)));
}

__device__ __forceinline__ uint32_t part1by2(uint32_t x) {
    x &= 0x3FFu;
    x = (x | (x << 16)) & 0x030000FFu;
    x = (x | (x << 8))  & 0x0300F00Fu;
    x = (x | (x << 4))  & 0x030C30C3u;
    x = (x | (x << 2))  & 0x09249249u;
    return x;
}
__device__ __forceinline__ uint32_t bucket_of(float px, float py, float pz) {
    const uint32_t bx = min(31u, (uint32_t)(px * 32.f));
    const uint32_t by = min(31u, (uint32_t)(py * 32.f));
    const uint32_t bz = min(31u, (uint32_t)(pz * 32.f));
    return part1by2(bx) | (part1by2(by) << 1) | (part1by2(bz) << 2);  // 15-bit Morton
}

// ---------------- sort kernels (counting sort by 32^3 Morton cell) ----------------
__global__ __launch_bounds__(256)
void hist_pass(const float* __restrict__ pts, uint32_t* __restrict__ hist) {
    int p = blockIdx.x * 1024 + threadIdx.x;
    #pragma unroll
    for (int k = 0; k < 4; ++k, p += 256) {
        const uint32_t b = bucket_of(pts[p * 3 + 0], pts[p * 3 + 1], pts[p * 3 + 2]);
        atomicAdd(&hist[b], 1u);
    }
}

__global__ __launch_bounds__(1024)
void scan_pass(const uint32_t* __restrict__ hist, uint32_t* __restrict__ cursor) {
    __shared__ uint32_t tsum[1024];
    const int t = threadIdx.x;
    uint32_t local[32];
    uint32_t s = 0;
    #pragma unroll
    for (int i = 0; i < 32; ++i) { local[i] = s; s += hist[t * 32 + i]; }
    tsum[t] = s;
    __syncthreads();
    for (int off = 1; off < 1024; off <<= 1) {
        const uint32_t v = (t >= off) ? tsum[t - off] : 0u;
        __syncthreads();
        tsum[t] += v;
        __syncthreads();
    }
    const uint32_t base = (t == 0) ? 0u : tsum[t - 1];
    #pragma unroll
    for (int i = 0; i < 32; ++i) cursor[t * 32 + i] = base + local[i];
}

__global__ __launch_bounds__(256)
void scatter_pass(const float* __restrict__ pts, uint32_t* __restrict__ cursor,
                  float* __restrict__ spts, uint32_t* __restrict__ perm) {
    int p = blockIdx.x * 1024 + threadIdx.x;
    #pragma unroll
    for (int k = 0; k < 4; ++k, p += 256) {
        const float px = pts[p * 3 + 0], py = pts[p * 3 + 1], pz = pts[p * 3 + 2];
        const uint32_t b = bucket_of(px, py, pz);
        const uint32_t d = atomicAdd(&cursor[b], 1u);
        spts[d * 3 + 0] = px; spts[d * 3 + 1] = py; spts[d * 3 + 2] = pz;
        perm[d] = (uint32_t)p;
    }
}

// ================= PASS 1: XCD-striped gather + parity x-pair merge ==========
// enc stores are NONTEMPORAL: streaming write-once data must not evict the
// 4MB table slice from this XCD's L2 (write-allocate pollution, R12 theory).
__global__ __launch_bounds__(256)
void hash_gather_pass(const float* __restrict__ points,
                      const float* __restrict__ table,
                      uint32_t* __restrict__ enc, ResParams rp)
{
    const int bid   = blockIdx.x;
    const int xcd   = bid & 7;
    const int j     = bid >> 3;
    const int lvl   = ((j >> 9) << 3) + xcd;
    const int chunk = j & 511;
    const float res = rp.r[lvl];
    const float* __restrict__ tl = table + (size_t)lvl * (size_t)(TSZ * 2u);
    uint32_t* __restrict__ el = enc + (size_t)lvl * (size_t)NPTS;
    const int pbase = chunk * 1024 + threadIdx.x;

    #pragma unroll
    for (int k = 0; k < 4; ++k) {
        const int p = pbase + k * 256;
        const float x0 = points[p * 3 + 0] * 0.5f + 0.5f;
        const float y0 = points[p * 3 + 1] * 0.5f + 0.5f;
        const float z0 = points[p * 3 + 2] * 0.5f + 0.5f;
        const float sx = x0 * res, sy = y0 * res, sz = z0 * res;
        const float fx = floorf(sx), fy = floorf(sy), fz = floorf(sz);
        const float tx = sx - fx,  ty = sy - fy,  tz = sz - fz;
        const uint32_t cx = (uint32_t)fx, cy = (uint32_t)fy, cz = (uint32_t)fz;
        const uint32_t hy0 = cy * PRIME1, hy1 = (cy + 1u) * PRIME1;
        const uint32_t hz0 = cz * PRIME2, hz1 = (cz + 1u) * PRIME2;
        const float wy[2] = {1.f - ty, ty};
        const float wz[2] = {1.f - tz, tz};
        const float wx0 = 1.f - tx, wx1 = tx;
        const bool cx_even = (cx & 1u) == 0u;

        float a0 = 0.f, a1 = 0.f;
        #pragma unroll
        for (int yz = 0; yz < 4; ++yz) {
            const uint32_t dy = (uint32_t)(yz & 1);
            const uint32_t dz = (uint32_t)(yz >> 1);
            const uint32_t h  = (dy ? hy1 : hy0) ^ (dz ? hz1 : hz0);
            const uint32_t i0 = (cx ^ h) & HMASK;
            const uint32_t i1 = ((cx + 1u) ^ h) & HMASK;
            float e0x, e0y, e1x, e1y;
            if (cx_even) {
                const float4 f4 = *reinterpret_cast<const float4*>(tl + (size_t)(i0 & ~1u) * 2u);
                const bool lo = (i0 & 1u) == 0u;
                e0x = lo ? f4.x : f4.z;  e0y = lo ? f4.y : f4.w;
                e1x = lo ? f4.z : f4.x;  e1y = lo ? f4.w : f4.y;
            } else {
                const float2 fa = *reinterpret_cast<const float2*>(tl + (size_t)i0 * 2u);
                const float2 fb = *reinterpret_cast<const float2*>(tl + (size_t)i1 * 2u);
                e0x = fa.x; e0y = fa.y; e1x = fb.x; e1y = fb.y;
            }
            const float wyz = wy[dy] * wz[dz];
            const float w0 = wyz * wx0, w1 = wyz * wx1;
            a0 = fmaf(w0, e0x, fmaf(w1, e1x, a0));
            a1 = fmaf(w0, e0y, fmaf(w1, e1y, a1));
        }
        __builtin_nontemporal_store(pack_f16x2(a0 * 1024.f, a1 * 1024.f), &el[p]);
    }
}

// ================= PASS 2: MFMA MLP, swapped orientation D[out][pt] =================
#define SW0T   0
#define SW1T   3328
#define SW2T   5632
#define SW3T   7936
#define SET    11392
#define SB0    18048
#define SB1    18176
#define SB2    18304
#define SB3    18432
#define SEB0   18624
#define SEW1   18880
#define SEB1   19136
#define SGEOM  19152
#define SMB    28368

__global__ __launch_bounds__(256)
void mlp_mfma(const uint32_t* __restrict__ enc,
              const uint32_t* __restrict__ perm,
              const float* __restrict__ W0, const float* __restrict__ b0,
              const float* __restrict__ W1, const float* __restrict__ b1,
              const float* __restrict__ W2, const float* __restrict__ b2,
              const float* __restrict__ W3, const float* __restrict__ b3,
              const float* __restrict__ eW0, const float* __restrict__ eb0,
              const float* __restrict__ eW1, const float* __restrict__ eb1,
              float* __restrict__ out)
{
    __shared__ __align__(16) unsigned char sm[SMB];
    _Float16* const w0t = (_Float16*)(sm + SW0T);
    _Float16* const w1t = (_Float16*)(sm + SW1T);
    _Float16* const w2t = (_Float16*)(sm + SW2T);
    _Float16* const w3t = (_Float16*)(sm + SW3T);
    _Float16* const et  = (_Float16*)(sm + SET);
    float* const b0s  = (float*)(sm + SB0);
    float* const b1s  = (float*)(sm + SB1);
    float* const b2s  = (float*)(sm + SB2);
    float* const b3s  = (float*)(sm + SB3);
    float* const eb0s = (float*)(sm + SEB0);
    float* const ew1s = (float*)(sm + SEW1);
    float* const eb1s = (float*)(sm + SEB1);

    const int tid = threadIdx.x;

    for (int i = tid; i < 1536; i += 256) { const int k = i >> 5, o = i & 31;
        w0t[o * 52 + k] = (_Float16)(W0[i] * (1.f / 1024.f)); }
    for (int i = tid; i < 1024; i += 256) { const int k = i >> 5, o = i & 31;
        w1t[o * 36 + k] = (_Float16)W1[i];
        w2t[o * 36 + k] = (_Float16)W2[i]; }
    for (int i = tid; i < 1536; i += 256) { const int o = i >> 5, k = i & 31;
        w3t[o * 36 + k] = (o < 33) ? (_Float16)W3[k * 33 + o] : (_Float16)0.f; }
    for (int i = tid; i < 3328; i += 256) {
        const int hd = i / 1664, rem = i - hd * 1664;
        const int hh = rem / 52, o = rem % 52;
        et[i] = (o >= 1 && o <= 32) ? (_Float16)eW0[hd * 1024 + (o - 1) * 32 + hh]
                                    : (_Float16)0.f;
    }
    for (int i = tid; i < 32; i += 256) { b0s[i] = b0[i]; b1s[i] = b1[i]; b2s[i] = b2[i]; }
    for (int i = tid; i < 48; i += 256) { b3s[i] = (i < 33) ? b3[i] : 0.f; }
    for (int i = tid; i < 64; i += 256) { eb0s[i] = eb0[i]; ew1s[i] = eW1[i]; }
    if (tid < 2) eb1s[tid] = eb1[tid];
    __syncthreads();

    const int wv = tid >> 6, l = tid & 63, g = l >> 4, lm = l & 15;
    const size_t ptbase = (size_t)blockIdx.x * 256 + (size_t)wv * 64;

    v4h bx[4][3];
    #pragma unroll
    for (int tt = 0; tt < 4; ++tt) {
        const size_t pt = ptbase + tt * 16 + lm;
        #pragma unroll
        for (int kc = 0; kc < 3; ++kc) {
            const int lv = 8 * kc + 2 * g;
            union { uint32_t u[2]; v4h h; } c;
            c.u[0] = enc[(size_t)lv * NPTS + pt];
            c.u[1] = enc[(size_t)(lv + 1) * NPTS + pt];
            bx[tt][kc] = c.h;
        }
    }

    v4f acc[2][4];
    #pragma unroll
    for (int m = 0; m < 2; ++m) {
        const v4f bi = *(const v4f*)(b0s + 16 * m + 4 * g);
        const v4h a0f = *(const v4h*)(w0t + (16 * m + lm) * 52 + 4 * g);
        const v4h a1f = *(const v4h*)(w0t + (16 * m + lm) * 52 + 16 + 4 * g);
        const v4h a2f = *(const v4h*)(w0t + (16 * m + lm) * 52 + 32 + 4 * g);
        #pragma unroll
        for (int tt = 0; tt < 4; ++tt) {
            v4f a = bi;
            a = MFMA16(a0f, bx[tt][0], a);
            a = MFMA16(a1f, bx[tt][1], a);
            a = MFMA16(a2f, bx[tt][2], a);
            acc[m][tt] = a;
        }
    }
    v4h bh[4][2];
    #pragma unroll
    for (int tt = 0; tt < 4; ++tt)
        #pragma unroll
        for (int m = 0; m < 2; ++m) {
            v4h h;
            #pragma unroll
            for (int r = 0; r < 4; ++r) h[r] = (_Float16)fmaxf(acc[m][tt][r], 0.f);
            bh[tt][m] = h;
        }

    #pragma unroll
    for (int m = 0; m < 2; ++m) {
        const v4f bi = *(const v4f*)(b1s + 16 * m + 4 * g);
        const v4h a0f = *(const v4h*)(w1t + (16 * m + lm) * 36 + 4 * g);
        const v4h a1f = *(const v4h*)(w1t + (16 * m + lm) * 36 + 16 + 4 * g);
        #pragma unroll
        for (int tt = 0; tt < 4; ++tt) {
            v4f a = bi;
            a = MFMA16(a0f, bh[tt][0], a);
            a = MFMA16(a1f, bh[tt][1], a);
            acc[m][tt] = a;
        }
    }
    #pragma unroll
    for (int tt = 0; tt < 4; ++tt)
        #pragma unroll
        for (int m = 0; m < 2; ++m) {
            v4h h;
            #pragma unroll
            for (int r = 0; r < 4; ++r) h[r] = (_Float16)fmaxf(acc[m][tt][r], 0.f);
            bh[tt][m] = h;
        }

    #pragma unroll
    for (int m = 0; m < 2; ++m) {
        const v4f bi = *(const v4f*)(b2s + 16 * m + 4 * g);
        const v4h a0f = *(const v4h*)(w2t + (16 * m + lm) * 36 + 4 * g);
        const v4h a1f = *(const v4h*)(w2t + (16 * m + lm) * 36 + 16 + 4 * g);
        #pragma unroll
        for (int tt = 0; tt < 4; ++tt) {
            v4f a = bi;
            a = MFMA16(a0f, bh[tt][0], a);
            a = MFMA16(a1f, bh[tt][1], a);
            acc[m][tt] = a;
        }
    }
    #pragma unroll
    for (int tt = 0; tt < 4; ++tt)
        #pragma unroll
        for (int m = 0; m < 2; ++m) {
            v4h h;
            #pragma unroll
            for (int r = 0; r < 4; ++r) h[r] = (_Float16)fmaxf(acc[m][tt][r], 0.f);
            bh[tt][m] = h;
        }

    v4f acc3[3][4];
    #pragma unroll
    for (int m = 0; m < 3; ++m) {
        const v4f bi = *(const v4f*)(b3s + 16 * m + 4 * g);
        const v4h a0f = *(const v4h*)(w3t + (16 * m + lm) * 36 + 4 * g);
        const v4h a1f = *(const v4h*)(w3t + (16 * m + lm) * 36 + 16 + 4 * g);
        #pragma unroll
        for (int tt = 0; tt < 4; ++tt) {
            v4f a = bi;
            a = MFMA16(a0f, bh[tt][0], a);
            a = MFMA16(a1f, bh[tt][1], a);
            acc3[m][tt] = a;
        }
    }
    v4h pf[4][3];
    #pragma unroll
    for (int tt = 0; tt < 4; ++tt)
        #pragma unroll
        for (int m = 0; m < 3; ++m) {
            v4h h;
            #pragma unroll
            for (int r = 0; r < 4; ++r) h[r] = (_Float16)acc3[m][tt][r];
            pf[tt][m] = h;
        }

    float ep[2][4];
    #pragma unroll
    for (int k = 0; k < 2; ++k) {
        const v4f bi0 = *(const v4f*)(eb0s + k * 32 + 4 * g);
        const v4f bi1 = *(const v4f*)(eb0s + k * 32 + 16 + 4 * g);
        const v4f w10 = *(const v4f*)(ew1s + k * 32 + 4 * g);
        const v4f w11 = *(const v4f*)(ew1s + k * 32 + 16 + 4 * g);
        const _Float16* eb = et + (size_t)k * 1664;
        const v4h e00 = *(const v4h*)(eb + lm * 52 + 4 * g);
        const v4h e01 = *(const v4h*)(eb + lm * 52 + 16 + 4 * g);
        const v4h e02 = *(const v4h*)(eb + lm * 52 + 32 + 4 * g);
        const v4h e10 = *(const v4h*)(eb + (16 + lm) * 52 + 4 * g);
        const v4h e11 = *(const v4h*)(eb + (16 + lm) * 52 + 16 + 4 * g);
        const v4h e12 = *(const v4h*)(eb + (16 + lm) * 52 + 32 + 4 * g);
        #pragma unroll
        for (int tt = 0; tt < 4; ++tt) {
            v4f h0 = bi0, h1 = bi1;
            h0 = MFMA16(e00, pf[tt][0], h0);
            h0 = MFMA16(e01, pf[tt][1], h0);
            h0 = MFMA16(e02, pf[tt][2], h0);
            h1 = MFMA16(e10, pf[tt][0], h1);
            h1 = MFMA16(e11, pf[tt][1], h1);
            h1 = MFMA16(e12, pf[tt][2], h1);
            float p = fmaxf(h0[0], 0.f) * w10[0] + fmaxf(h0[1], 0.f) * w10[1]
                    + fmaxf(h0[2], 0.f) * w10[2] + fmaxf(h0[3], 0.f) * w10[3]
                    + fmaxf(h1[0], 0.f) * w11[0] + fmaxf(h1[1], 0.f) * w11[1]
                    + fmaxf(h1[2], 0.f) * w11[2] + fmaxf(h1[3], 0.f) * w11[3];
            p += __shfl_xor(p, 16);
            p += __shfl_xor(p, 32);
            ep[k][tt] = p + eb1s[k];
        }
    }

    // ---- epilogue: LDS bounce; perm-redirected NONTEMPORAL output stores ----
    float* const gw = (float*)(sm + SGEOM) + wv * (16 * 36);
    #pragma unroll
    for (int tt = 0; tt < 4; ++tt) {
        #pragma unroll
        for (int m = 0; m < 3; ++m)
            #pragma unroll
            for (int r = 0; r < 4; ++r) {
                const int o = 16 * m + 4 * g + r;
                if (o >= 1 && o <= 32) gw[lm * 36 + o - 1] = acc3[m][tt][r];
            }
        __syncthreads();
        {
            const int pl = l >> 2, q = l & 3;
            const size_t s = ptbase + tt * 16 + pl;
            const size_t opid = perm ? (size_t)perm[s] : s;
            const v4f g0 = *(const v4f*)(gw + pl * 36 + q * 8);
            const v4f g1 = *(const v4f*)(gw + pl * 36 + q * 8 + 4);
            float* og = out + (size_t)NPTS * 6 + opid * 32 + q * 8;
            __builtin_nontemporal_store(g0, (v4f*)og);
            __builtin_nontemporal_store(g1, (v4f*)(og + 4));
        }
        if (l < 16) {
            const size_t s = ptbase + tt * 16 + l;
            const size_t pid = perm ? (size_t)perm[s] : s;
            const float sdf   = acc3[0][tt][0];
            const float inner = softplus_f(ep[1][tt]);
            const float outer = -softplus_f(ep[0][tt]);
            __builtin_nontemporal_store(sdf + inner + 1e-4f, &out[pid * 3 + 0]);
            __builtin_nontemporal_store(sdf,                 &out[pid * 3 + 1]);
            __builtin_nontemporal_store(sdf + outer - 1e-4f, &out[pid * 3 + 2]);
            float* oo = out + (size_t)NPTS * 3 + pid * 3;
            __builtin_nontemporal_store(inner, &oo[0]);
            __builtin_nontemporal_store(0.f,   &oo[1]);
            __builtin_nontemporal_store(outer, &oo[2]);
        }
        __syncthreads();
    }
}

extern "C" void kernel_launch(void* const* d_in, const int* in_sizes, int n_in,
                              void* d_out, int out_size, void* d_ws, size_t ws_size,
                              hipStream_t stream) {
    const float* points = (const float*)d_in[0];
    const float* table  = (const float*)d_in[1];
    const float* W0  = (const float*)d_in[2];
    const float* b0  = (const float*)d_in[3];
    const float* W1  = (const float*)d_in[4];
    const float* b1  = (const float*)d_in[5];
    const float* W2  = (const float*)d_in[6];
    const float* b2  = (const float*)d_in[7];
    const float* W3  = (const float*)d_in[8];
    const float* b3  = (const float*)d_in[9];
    const float* eW0 = (const float*)d_in[10];
    const float* eb0 = (const float*)d_in[11];
    const float* eW1 = (const float*)d_in[12];
    const float* eb1 = (const float*)d_in[13];
    float* out = (float*)d_out;

    ResParams rp;
    for (int l = 0; l < NLVL; ++l)
        rp.r[l] = (float)floor(16.0 * exp((double)l * log(2048.0 / 16.0) / 23.0));
    (void)in_sizes; (void)n_in; (void)out_size;

    const size_t ENC_B  = (size_t)NLVL * NPTS * 4;
    const size_t SPTS_B = (size_t)NPTS * 3 * 4;
    const size_t PERM_B = (size_t)NPTS * 4;
    const size_t HIST_B = (size_t)NBKT * 4;
    const size_t WS_NEEDED = ENC_B + SPTS_B + PERM_B + 2 * HIST_B;

    uint32_t* enc = (uint32_t*)d_ws;

    if (ws_size >= WS_NEEDED) {
        float*    spts   = (float*)((char*)d_ws + ENC_B);
        uint32_t* perm   = (uint32_t*)((char*)d_ws + ENC_B + SPTS_B);
        uint32_t* hist   = (uint32_t*)((char*)d_ws + ENC_B + SPTS_B + PERM_B);
        uint32_t* cursor = (uint32_t*)((char*)d_ws + ENC_B + SPTS_B + PERM_B + HIST_B);

        hipMemsetAsync(hist, 0, HIST_B, stream);
        hist_pass<<<dim3(NPTS / 1024), dim3(256), 0, stream>>>(points, hist);
        scan_pass<<<dim3(1), dim3(1024), 0, stream>>>(hist, cursor);
        scatter_pass<<<dim3(NPTS / 1024), dim3(256), 0, stream>>>(points, cursor, spts, perm);
        hash_gather_pass<<<dim3(NLVL * 512), dim3(256), 0, stream>>>(spts, table, enc, rp);
        mlp_mfma<<<dim3(NPTS / 256), dim3(256), 0, stream>>>(
            enc, perm, W0, b0, W1, b1, W2, b2, W3, b3, eW0, eb0, eW1, eb1, out);
    } else {
        hash_gather_pass<<<dim3(NLVL * 512), dim3(256), 0, stream>>>(points, table, enc, rp);
        mlp_mfma<<<dim3(NPTS / 256), dim3(256), 0, stream>>>(
            enc, (const uint32_t*)nullptr, W0, b0, W1, b1, W2, b2, W3, b3,
            eW0, eb0, eW1, eb1, out);
    }
}

// Round 13
// 333.774 us; speedup vs baseline: 1.0419x; 1.0419x over previous
//
#include <hip/hip_runtime.h>
#include <math.h>
#include <stdint.h>

#define NPTS   524288
#define TSZ    524288u
#define HMASK  (TSZ - 1u)
#define PRIME1 2654435761u
#define PRIME2 805459861u
#define NLVL   24

typedef float    v4f __attribute__((ext_vector_type(4)));
typedef _Float16 v4h __attribute__((ext_vector_type(4)));

#define MFMA16(A,B,C) __builtin_amdgcn_mfma_f32_16x16x16f16((A),(B),(C),0,0,0)

struct ResParams { float r[NLVL]; };

__device__ __forceinline__ uint32_t pack_f16x2(float a, float b) {
    union { _Float16 h[2]; uint32_t u; } c;
    c.h[0] = (_Float16)a; c.h[1] = (_Float16)b;
    return c.u;
}

__device__ __forceinline__ float softplus_f(float x) {
    return fmaxf(x, 0.f) + log1pf(expf(-fabsf(x)));
}

// ======== PASS 1: XCD-striped gather, parity x-pair merge, 8 pts/thread =========
// ILP probe: fully-unrolled 8-point body exposes ~48 independent loads per wave.
// XCD x owns levels {x, x+8, x+16} (3 phases of 256 chunk-blocks each).
__global__ __launch_bounds__(256)
void hash_gather_pass(const float* __restrict__ points,
                      const float* __restrict__ table,
                      uint32_t* __restrict__ enc, ResParams rp)
{
    const int bid   = blockIdx.x;
    const int xcd   = bid & 7;
    const int j     = bid >> 3;               // 0..767
    const int lvl   = ((j >> 8) << 3) + xcd;  // phase*8 + xcd
    const int chunk = j & 255;                // 256 chunks of 2048 points
    const float res = rp.r[lvl];
    const float* __restrict__ tl = table + (size_t)lvl * (size_t)(TSZ * 2u);
    uint32_t* __restrict__ el = enc + (size_t)lvl * (size_t)NPTS;
    const int pbase = chunk * 2048 + threadIdx.x;

    #pragma unroll
    for (int k = 0; k < 8; ++k) {
        const int p = pbase + k * 256;
        const float x0 = points[p * 3 + 0] * 0.5f + 0.5f;
        const float y0 = points[p * 3 + 1] * 0.5f + 0.5f;
        const float z0 = points[p * 3 + 2] * 0.5f + 0.5f;
        const float sx = x0 * res, sy = y0 * res, sz = z0 * res;
        const float fx = floorf(sx), fy = floorf(sy), fz = floorf(sz);
        const float tx = sx - fx,  ty = sy - fy,  tz = sz - fz;
        const uint32_t cx = (uint32_t)fx, cy = (uint32_t)fy, cz = (uint32_t)fz;
        const uint32_t hy0 = cy * PRIME1, hy1 = (cy + 1u) * PRIME1;
        const uint32_t hz0 = cz * PRIME2, hz1 = (cz + 1u) * PRIME2;
        const float wy[2] = {1.f - ty, ty};
        const float wz[2] = {1.f - tz, tz};
        const float wx0 = 1.f - tx, wx1 = tx;
        const bool cx_even = (cx & 1u) == 0u;

        float a0 = 0.f, a1 = 0.f;
        #pragma unroll
        for (int yz = 0; yz < 4; ++yz) {
            const uint32_t dy = (uint32_t)(yz & 1);
            const uint32_t dz = (uint32_t)(yz >> 1);
            const uint32_t h  = (dy ? hy1 : hy0) ^ (dz ? hz1 : hz0);
            const uint32_t i0 = (cx ^ h) & HMASK;
            const uint32_t i1 = ((cx + 1u) ^ h) & HMASK;
            float e0x, e0y, e1x, e1y;
            if (cx_even) {
                const float4 f4 = *reinterpret_cast<const float4*>(tl + (size_t)(i0 & ~1u) * 2u);
                const bool lo = (i0 & 1u) == 0u;
                e0x = lo ? f4.x : f4.z;  e0y = lo ? f4.y : f4.w;
                e1x = lo ? f4.z : f4.x;  e1y = lo ? f4.w : f4.y;
            } else {
                const float2 fa = *reinterpret_cast<const float2*>(tl + (size_t)i0 * 2u);
                const float2 fb = *reinterpret_cast<const float2*>(tl + (size_t)i1 * 2u);
                e0x = fa.x; e0y = fa.y; e1x = fb.x; e1y = fb.y;
            }
            const float wyz = wy[dy] * wz[dz];
            const float w0 = wyz * wx0, w1 = wyz * wx1;
            a0 = fmaf(w0, e0x, fmaf(w1, e1x, a0));
            a1 = fmaf(w0, e0y, fmaf(w1, e1y, a1));
        }
        __builtin_nontemporal_store(pack_f16x2(a0 * 1024.f, a1 * 1024.f), &el[p]);
    }
}

// ================= PASS 2: MFMA MLP, swapped orientation D[out][pt] =================
#define SW0T   0
#define SW1T   3328
#define SW2T   5632
#define SW3T   7936
#define SET    11392
#define SB0    18048
#define SB1    18176
#define SB2    18304
#define SB3    18432
#define SEB0   18624
#define SEW1   18880
#define SEB1   19136
#define SGEOM  19152
#define SMB    28368

__global__ __launch_bounds__(256)
void mlp_mfma(const uint32_t* __restrict__ enc,
              const float* __restrict__ W0, const float* __restrict__ b0,
              const float* __restrict__ W1, const float* __restrict__ b1,
              const float* __restrict__ W2, const float* __restrict__ b2,
              const float* __restrict__ W3, const float* __restrict__ b3,
              const float* __restrict__ eW0, const float* __restrict__ eb0,
              const float* __restrict__ eW1, const float* __restrict__ eb1,
              float* __restrict__ out)
{
    __shared__ __align__(16) unsigned char sm[SMB];
    _Float16* const w0t = (_Float16*)(sm + SW0T);
    _Float16* const w1t = (_Float16*)(sm + SW1T);
    _Float16* const w2t = (_Float16*)(sm + SW2T);
    _Float16* const w3t = (_Float16*)(sm + SW3T);
    _Float16* const et  = (_Float16*)(sm + SET);
    float* const b0s  = (float*)(sm + SB0);
    float* const b1s  = (float*)(sm + SB1);
    float* const b2s  = (float*)(sm + SB2);
    float* const b3s  = (float*)(sm + SB3);
    float* const eb0s = (float*)(sm + SEB0);
    float* const ew1s = (float*)(sm + SEW1);
    float* const eb1s = (float*)(sm + SEB1);

    const int tid = threadIdx.x;

    for (int i = tid; i < 1536; i += 256) { const int k = i >> 5, o = i & 31;
        w0t[o * 52 + k] = (_Float16)(W0[i] * (1.f / 1024.f)); }
    for (int i = tid; i < 1024; i += 256) { const int k = i >> 5, o = i & 31;
        w1t[o * 36 + k] = (_Float16)W1[i];
        w2t[o * 36 + k] = (_Float16)W2[i]; }
    for (int i = tid; i < 1536; i += 256) { const int o = i >> 5, k = i & 31;
        w3t[o * 36 + k] = (o < 33) ? (_Float16)W3[k * 33 + o] : (_Float16)0.f; }
    for (int i = tid; i < 3328; i += 256) {
        const int hd = i / 1664, rem = i - hd * 1664;
        const int hh = rem / 52, o = rem % 52;
        et[i] = (o >= 1 && o <= 32) ? (_Float16)eW0[hd * 1024 + (o - 1) * 32 + hh]
                                    : (_Float16)0.f;
    }
    for (int i = tid; i < 32; i += 256) { b0s[i] = b0[i]; b1s[i] = b1[i]; b2s[i] = b2[i]; }
    for (int i = tid; i < 48; i += 256) { b3s[i] = (i < 33) ? b3[i] : 0.f; }
    for (int i = tid; i < 64; i += 256) { eb0s[i] = eb0[i]; ew1s[i] = eW1[i]; }
    if (tid < 2) eb1s[tid] = eb1[tid];
    __syncthreads();

    const int wv = tid >> 6, l = tid & 63, g = l >> 4, lm = l & 15;
    const size_t ptbase = (size_t)blockIdx.x * 256 + (size_t)wv * 64;

    v4h bx[4][3];
    #pragma unroll
    for (int tt = 0; tt < 4; ++tt) {
        const size_t pt = ptbase + tt * 16 + lm;
        #pragma unroll
        for (int kc = 0; kc < 3; ++kc) {
            const int lv = 8 * kc + 2 * g;
            union { uint32_t u[2]; v4h h; } c;
            c.u[0] = enc[(size_t)lv * NPTS + pt];
            c.u[1] = enc[(size_t)(lv + 1) * NPTS + pt];
            bx[tt][kc] = c.h;
        }
    }

    v4f acc[2][4];
    #pragma unroll
    for (int m = 0; m < 2; ++m) {
        const v4f bi = *(const v4f*)(b0s + 16 * m + 4 * g);
        const v4h a0f = *(const v4h*)(w0t + (16 * m + lm) * 52 + 4 * g);
        const v4h a1f = *(const v4h*)(w0t + (16 * m + lm) * 52 + 16 + 4 * g);
        const v4h a2f = *(const v4h*)(w0t + (16 * m + lm) * 52 + 32 + 4 * g);
        #pragma unroll
        for (int tt = 0; tt < 4; ++tt) {
            v4f a = bi;
            a = MFMA16(a0f, bx[tt][0], a);
            a = MFMA16(a1f, bx[tt][1], a);
            a = MFMA16(a2f, bx[tt][2], a);
            acc[m][tt] = a;
        }
    }
    v4h bh[4][2];
    #pragma unroll
    for (int tt = 0; tt < 4; ++tt)
        #pragma unroll
        for (int m = 0; m < 2; ++m) {
            v4h h;
            #pragma unroll
            for (int r = 0; r < 4; ++r) h[r] = (_Float16)fmaxf(acc[m][tt][r], 0.f);
            bh[tt][m] = h;
        }

    #pragma unroll
    for (int m = 0; m < 2; ++m) {
        const v4f bi = *(const v4f*)(b1s + 16 * m + 4 * g);
        const v4h a0f = *(const v4h*)(w1t + (16 * m + lm) * 36 + 4 * g);
        const v4h a1f = *(const v4h*)(w1t + (16 * m + lm) * 36 + 16 + 4 * g);
        #pragma unroll
        for (int tt = 0; tt < 4; ++tt) {
            v4f a = bi;
            a = MFMA16(a0f, bh[tt][0], a);
            a = MFMA16(a1f, bh[tt][1], a);
            acc[m][tt] = a;
        }
    }
    #pragma unroll
    for (int tt = 0; tt < 4; ++tt)
        #pragma unroll
        for (int m = 0; m < 2; ++m) {
            v4h h;
            #pragma unroll
            for (int r = 0; r < 4; ++r) h[r] = (_Float16)fmaxf(acc[m][tt][r], 0.f);
            bh[tt][m] = h;
        }

    #pragma unroll
    for (int m = 0; m < 2; ++m) {
        const v4f bi = *(const v4f*)(b2s + 16 * m + 4 * g);
        const v4h a0f = *(const v4h*)(w2t + (16 * m + lm) * 36 + 4 * g);
        const v4h a1f = *(const v4h*)(w2t + (16 * m + lm) * 36 + 16 + 4 * g);
        #pragma unroll
        for (int tt = 0; tt < 4; ++tt) {
            v4f a = bi;
            a = MFMA16(a0f, bh[tt][0], a);
            a = MFMA16(a1f, bh[tt][1], a);
            acc[m][tt] = a;
        }
    }
    #pragma unroll
    for (int tt = 0; tt < 4; ++tt)
        #pragma unroll
        for (int m = 0; m < 2; ++m) {
            v4h h;
            #pragma unroll
            for (int r = 0; r < 4; ++r) h[r] = (_Float16)fmaxf(acc[m][tt][r], 0.f);
            bh[tt][m] = h;
        }

    v4f acc3[3][4];
    #pragma unroll
    for (int m = 0; m < 3; ++m) {
        const v4f bi = *(const v4f*)(b3s + 16 * m + 4 * g);
        const v4h a0f = *(const v4h*)(w3t + (16 * m + lm) * 36 + 4 * g);
        const v4h a1f = *(const v4h*)(w3t + (16 * m + lm) * 36 + 16 + 4 * g);
        #pragma unroll
        for (int tt = 0; tt < 4; ++tt) {
            v4f a = bi;
            a = MFMA16(a0f, bh[tt][0], a);
            a = MFMA16(a1f, bh[tt][1], a);
            acc3[m][tt] = a;
        }
    }
    v4h pf[4][3];
    #pragma unroll
    for (int tt = 0; tt < 4; ++tt)
        #pragma unroll
        for (int m = 0; m < 3; ++m) {
            v4h h;
            #pragma unroll
            for (int r = 0; r < 4; ++r) h[r] = (_Float16)acc3[m][tt][r];
            pf[tt][m] = h;
        }

    float ep[2][4];
    #pragma unroll
    for (int k = 0; k < 2; ++k) {
        const v4f bi0 = *(const v4f*)(eb0s + k * 32 + 4 * g);
        const v4f bi1 = *(const v4f*)(eb0s + k * 32 + 16 + 4 * g);
        const v4f w10 = *(const v4f*)(ew1s + k * 32 + 4 * g);
        const v4f w11 = *(const v4f*)(ew1s + k * 32 + 16 + 4 * g);
        const _Float16* eb = et + (size_t)k * 1664;
        const v4h e00 = *(const v4h*)(eb + lm * 52 + 4 * g);
        const v4h e01 = *(const v4h*)(eb + lm * 52 + 16 + 4 * g);
        const v4h e02 = *(const v4h*)(eb + lm * 52 + 32 + 4 * g);
        const v4h e10 = *(const v4h*)(eb + (16 + lm) * 52 + 4 * g);
        const v4h e11 = *(const v4h*)(eb + (16 + lm) * 52 + 16 + 4 * g);
        const v4h e12 = *(const v4h*)(eb + (16 + lm) * 52 + 32 + 4 * g);
        #pragma unroll
        for (int tt = 0; tt < 4; ++tt) {
            v4f h0 = bi0, h1 = bi1;
            h0 = MFMA16(e00, pf[tt][0], h0);
            h0 = MFMA16(e01, pf[tt][1], h0);
            h0 = MFMA16(e02, pf[tt][2], h0);
            h1 = MFMA16(e10, pf[tt][0], h1);
            h1 = MFMA16(e11, pf[tt][1], h1);
            h1 = MFMA16(e12, pf[tt][2], h1);
            float p = fmaxf(h0[0], 0.f) * w10[0] + fmaxf(h0[1], 0.f) * w10[1]
                    + fmaxf(h0[2], 0.f) * w10[2] + fmaxf(h0[3], 0.f) * w10[3]
                    + fmaxf(h1[0], 0.f) * w11[0] + fmaxf(h1[1], 0.f) * w11[1]
                    + fmaxf(h1[2], 0.f) * w11[2] + fmaxf(h1[3], 0.f) * w11[3];
            p += __shfl_xor(p, 16);
            p += __shfl_xor(p, 32);
            ep[k][tt] = p + eb1s[k];
        }
    }

    // ---- epilogue: LDS bounce, sequential cached stores (original point order) ----
    float* const gw = (float*)(sm + SGEOM) + wv * (16 * 36);
    #pragma unroll
    for (int tt = 0; tt < 4; ++tt) {
        #pragma unroll
        for (int m = 0; m < 3; ++m)
            #pragma unroll
            for (int r = 0; r < 4; ++r) {
                const int o = 16 * m + 4 * g + r;
                if (o >= 1 && o <= 32) gw[lm * 36 + o - 1] = acc3[m][tt][r];
            }
        __syncthreads();
        {
            const int pl = l >> 2, q = l & 3;
            const size_t pid = ptbase + tt * 16 + pl;
            const v4f g0 = *(const v4f*)(gw + pl * 36 + q * 8);
            const v4f g1 = *(const v4f*)(gw + pl * 36 + q * 8 + 4);
            float* og = out + (size_t)NPTS * 6 + pid * 32 + q * 8;
            *reinterpret_cast<v4f*>(og)     = g0;
            *reinterpret_cast<v4f*>(og + 4) = g1;
        }
        if (l < 16) {
            const size_t pid = ptbase + tt * 16 + l;
            const float sdf   = acc3[0][tt][0];
            const float inner = softplus_f(ep[1][tt]);
            const float outer = -softplus_f(ep[0][tt]);
            out[pid * 3 + 0] = sdf + inner + 1e-4f;
            out[pid * 3 + 1] = sdf;
            out[pid * 3 + 2] = sdf + outer - 1e-4f;
            float* oo = out + (size_t)NPTS * 3 + pid * 3;
            oo[0] = inner; oo[1] = 0.f; oo[2] = outer;
        }
        __syncthreads();
    }
}

extern "C" void kernel_launch(void* const* d_in, const int* in_sizes, int n_in,
                              void* d_out, int out_size, void* d_ws, size_t ws_size,
                              hipStream_t stream) {
    const float* points = (const float*)d_in[0];
    const float* table  = (const float*)d_in[1];
    const float* W0  = (const float*)d_in[2];
    const float* b0  = (const float*)d_in[3];
    const float* W1  = (const float*)d_in[4];
    const float* b1  = (const float*)d_in[5];
    const float* W2  = (const float*)d_in[6];
    const float* b2  = (const float*)d_in[7];
    const float* W3  = (const float*)d_in[8];
    const float* b3  = (const float*)d_in[9];
    const float* eW0 = (const float*)d_in[10];
    const float* eb0 = (const float*)d_in[11];
    const float* eW1 = (const float*)d_in[12];
    const float* eb1 = (const float*)d_in[13];
    float* out = (float*)d_out;

    ResParams rp;
    for (int l = 0; l < NLVL; ++l)
        rp.r[l] = (float)floor(16.0 * exp((double)l * log(2048.0 / 16.0) / 23.0));
    (void)in_sizes; (void)n_in; (void)out_size; (void)ws_size;

    uint32_t* enc = (uint32_t*)d_ws;   // 50.3 MB
    hash_gather_pass<<<dim3(NLVL * 256), dim3(256), 0, stream>>>(points, table, enc, rp);
    mlp_mfma<<<dim3(NPTS / 256), dim3(256), 0, stream>>>(
        enc, W0, b0, W1, b1, W2, b2, W3, b3, eW0, eb0, eW1, eb1, out);
}

// Round 14
// 316.409 us; speedup vs baseline: 1.0990x; 1.0549x over previous
//
#include <hip/hip_runtime.h>
#include <math.h>
#include <stdint.h>

#define NPTS   524288
#define TSZ    524288u
#define HMASK  (TSZ - 1u)
#define PRIME1 2654435761u
#define PRIME2 805459861u
#define NLVL   24

typedef float    v4f __attribute__((ext_vector_type(4)));
typedef _Float16 v4h __attribute__((ext_vector_type(4)));

#define MFMA16(A,B,C) __builtin_amdgcn_mfma_f32_16x16x16f16((A),(B),(C),0,0,0)

struct ResParams { float r[NLVL]; };

__device__ __forceinline__ uint32_t pack_f16x2(float a, float b) {
    union { _Float16 h[2]; uint32_t u; } c;
    c.h[0] = (_Float16)a; c.h[1] = (_Float16)b;
    return c.u;
}

__device__ __forceinline__ float softplus_f(float x) {
    return fmaxf(x, 0.f) + log1pf(expf(-fabsf(x)));
}

// ================= PASS 1: XCD-striped gather + parity x-pair merge ==========
// R10 configuration — measured 276 us, within ~4% of the L2 request-throughput
// floor (75.5M requests at ~14.6 req/cy/XCD). 4 pts/thread, 512 chunks/level:
// keeps the per-level resident window tight (R13 showed 8 pts/thread thrashes).
__global__ __launch_bounds__(256)
void hash_gather_pass(const float* __restrict__ points,
                      const float* __restrict__ table,
                      uint32_t* __restrict__ enc, ResParams rp)
{
    const int bid   = blockIdx.x;
    const int xcd   = bid & 7;
    const int j     = bid >> 3;
    const int lvl   = ((j >> 9) << 3) + xcd;  // XCD x owns levels {x, x+8, x+16}
    const int chunk = j & 511;
    const float res = rp.r[lvl];
    const float* __restrict__ tl = table + (size_t)lvl * (size_t)(TSZ * 2u);
    uint32_t* __restrict__ el = enc + (size_t)lvl * (size_t)NPTS;
    const int pbase = chunk * 1024 + threadIdx.x;

    #pragma unroll
    for (int k = 0; k < 4; ++k) {
        const int p = pbase + k * 256;
        const float x0 = points[p * 3 + 0] * 0.5f + 0.5f;
        const float y0 = points[p * 3 + 1] * 0.5f + 0.5f;
        const float z0 = points[p * 3 + 2] * 0.5f + 0.5f;
        const float sx = x0 * res, sy = y0 * res, sz = z0 * res;
        const float fx = floorf(sx), fy = floorf(sy), fz = floorf(sz);
        const float tx = sx - fx,  ty = sy - fy,  tz = sz - fz;
        const uint32_t cx = (uint32_t)fx, cy = (uint32_t)fy, cz = (uint32_t)fz;
        const uint32_t hy0 = cy * PRIME1, hy1 = (cy + 1u) * PRIME1;
        const uint32_t hz0 = cz * PRIME2, hz1 = (cz + 1u) * PRIME2;
        const float wy[2] = {1.f - ty, ty};
        const float wz[2] = {1.f - tz, tz};
        const float wx0 = 1.f - tx, wx1 = tx;
        const bool cx_even = (cx & 1u) == 0u;

        float a0 = 0.f, a1 = 0.f;
        #pragma unroll
        for (int yz = 0; yz < 4; ++yz) {
            const uint32_t dy = (uint32_t)(yz & 1);
            const uint32_t dz = (uint32_t)(yz >> 1);
            const uint32_t h  = (dy ? hy1 : hy0) ^ (dz ? hz1 : hz0);
            const uint32_t i0 = (cx ^ h) & HMASK;
            const uint32_t i1 = ((cx + 1u) ^ h) & HMASK;
            float e0x, e0y, e1x, e1y;
            if (cx_even) {
                const float4 f4 = *reinterpret_cast<const float4*>(tl + (size_t)(i0 & ~1u) * 2u);
                const bool lo = (i0 & 1u) == 0u;
                e0x = lo ? f4.x : f4.z;  e0y = lo ? f4.y : f4.w;
                e1x = lo ? f4.z : f4.x;  e1y = lo ? f4.w : f4.y;
            } else {
                const float2 fa = *reinterpret_cast<const float2*>(tl + (size_t)i0 * 2u);
                const float2 fb = *reinterpret_cast<const float2*>(tl + (size_t)i1 * 2u);
                e0x = fa.x; e0y = fa.y; e1x = fb.x; e1y = fb.y;
            }
            const float wyz = wy[dy] * wz[dz];
            const float w0 = wyz * wx0, w1 = wyz * wx1;
            a0 = fmaf(w0, e0x, fmaf(w1, e1x, a0));
            a1 = fmaf(w0, e0y, fmaf(w1, e1y, a1));
        }
        el[p] = pack_f16x2(a0 * 1024.f, a1 * 1024.f);
    }
}

// ================= PASS 2: MFMA MLP, swapped orientation D[out][pt] =================
#define SW0T   0
#define SW1T   3328
#define SW2T   5632
#define SW3T   7936
#define SET    11392
#define SB0    18048
#define SB1    18176
#define SB2    18304
#define SB3    18432
#define SEB0   18624
#define SEW1   18880
#define SEB1   19136
#define SGEOM  19152
#define SMB    28368

__global__ __launch_bounds__(256)
void mlp_mfma(const uint32_t* __restrict__ enc,
              const float* __restrict__ W0, const float* __restrict__ b0,
              const float* __restrict__ W1, const float* __restrict__ b1,
              const float* __restrict__ W2, const float* __restrict__ b2,
              const float* __restrict__ W3, const float* __restrict__ b3,
              const float* __restrict__ eW0, const float* __restrict__ eb0,
              const float* __restrict__ eW1, const float* __restrict__ eb1,
              float* __restrict__ out)
{
    __shared__ __align__(16) unsigned char sm[SMB];
    _Float16* const w0t = (_Float16*)(sm + SW0T);
    _Float16* const w1t = (_Float16*)(sm + SW1T);
    _Float16* const w2t = (_Float16*)(sm + SW2T);
    _Float16* const w3t = (_Float16*)(sm + SW3T);
    _Float16* const et  = (_Float16*)(sm + SET);
    float* const b0s  = (float*)(sm + SB0);
    float* const b1s  = (float*)(sm + SB1);
    float* const b2s  = (float*)(sm + SB2);
    float* const b3s  = (float*)(sm + SB3);
    float* const eb0s = (float*)(sm + SEB0);
    float* const ew1s = (float*)(sm + SEW1);
    float* const eb1s = (float*)(sm + SEB1);

    const int tid = threadIdx.x;

    for (int i = tid; i < 1536; i += 256) { const int k = i >> 5, o = i & 31;
        w0t[o * 52 + k] = (_Float16)(W0[i] * (1.f / 1024.f)); }
    for (int i = tid; i < 1024; i += 256) { const int k = i >> 5, o = i & 31;
        w1t[o * 36 + k] = (_Float16)W1[i];
        w2t[o * 36 + k] = (_Float16)W2[i]; }
    for (int i = tid; i < 1536; i += 256) { const int o = i >> 5, k = i & 31;
        w3t[o * 36 + k] = (o < 33) ? (_Float16)W3[k * 33 + o] : (_Float16)0.f; }
    for (int i = tid; i < 3328; i += 256) {
        const int hd = i / 1664, rem = i - hd * 1664;
        const int hh = rem / 52, o = rem % 52;
        et[i] = (o >= 1 && o <= 32) ? (_Float16)eW0[hd * 1024 + (o - 1) * 32 + hh]
                                    : (_Float16)0.f;
    }
    for (int i = tid; i < 32; i += 256) { b0s[i] = b0[i]; b1s[i] = b1[i]; b2s[i] = b2[i]; }
    for (int i = tid; i < 48; i += 256) { b3s[i] = (i < 33) ? b3[i] : 0.f; }
    for (int i = tid; i < 64; i += 256) { eb0s[i] = eb0[i]; ew1s[i] = eW1[i]; }
    if (tid < 2) eb1s[tid] = eb1[tid];
    __syncthreads();

    const int wv = tid >> 6, l = tid & 63, g = l >> 4, lm = l & 15;
    const size_t ptbase = (size_t)blockIdx.x * 256 + (size_t)wv * 64;

    v4h bx[4][3];
    #pragma unroll
    for (int tt = 0; tt < 4; ++tt) {
        const size_t pt = ptbase + tt * 16 + lm;
        #pragma unroll
        for (int kc = 0; kc < 3; ++kc) {
            const int lv = 8 * kc + 2 * g;
            union { uint32_t u[2]; v4h h; } c;
            c.u[0] = enc[(size_t)lv * NPTS + pt];
            c.u[1] = enc[(size_t)(lv + 1) * NPTS + pt];
            bx[tt][kc] = c.h;
        }
    }

    v4f acc[2][4];
    #pragma unroll
    for (int m = 0; m < 2; ++m) {
        const v4f bi = *(const v4f*)(b0s + 16 * m + 4 * g);
        const v4h a0f = *(const v4h*)(w0t + (16 * m + lm) * 52 + 4 * g);
        const v4h a1f = *(const v4h*)(w0t + (16 * m + lm) * 52 + 16 + 4 * g);
        const v4h a2f = *(const v4h*)(w0t + (16 * m + lm) * 52 + 32 + 4 * g);
        #pragma unroll
        for (int tt = 0; tt < 4; ++tt) {
            v4f a = bi;
            a = MFMA16(a0f, bx[tt][0], a);
            a = MFMA16(a1f, bx[tt][1], a);
            a = MFMA16(a2f, bx[tt][2], a);
            acc[m][tt] = a;
        }
    }
    v4h bh[4][2];
    #pragma unroll
    for (int tt = 0; tt < 4; ++tt)
        #pragma unroll
        for (int m = 0; m < 2; ++m) {
            v4h h;
            #pragma unroll
            for (int r = 0; r < 4; ++r) h[r] = (_Float16)fmaxf(acc[m][tt][r], 0.f);
            bh[tt][m] = h;
        }

    #pragma unroll
    for (int m = 0; m < 2; ++m) {
        const v4f bi = *(const v4f*)(b1s + 16 * m + 4 * g);
        const v4h a0f = *(const v4h*)(w1t + (16 * m + lm) * 36 + 4 * g);
        const v4h a1f = *(const v4h*)(w1t + (16 * m + lm) * 36 + 16 + 4 * g);
        #pragma unroll
        for (int tt = 0; tt < 4; ++tt) {
            v4f a = bi;
            a = MFMA16(a0f, bh[tt][0], a);
            a = MFMA16(a1f, bh[tt][1], a);
            acc[m][tt] = a;
        }
    }
    #pragma unroll
    for (int tt = 0; tt < 4; ++tt)
        #pragma unroll
        for (int m = 0; m < 2; ++m) {
            v4h h;
            #pragma unroll
            for (int r = 0; r < 4; ++r) h[r] = (_Float16)fmaxf(acc[m][tt][r], 0.f);
            bh[tt][m] = h;
        }

    #pragma unroll
    for (int m = 0; m < 2; ++m) {
        const v4f bi = *(const v4f*)(b2s + 16 * m + 4 * g);
        const v4h a0f = *(const v4h*)(w2t + (16 * m + lm) * 36 + 4 * g);
        const v4h a1f = *(const v4h*)(w2t + (16 * m + lm) * 36 + 16 + 4 * g);
        #pragma unroll
        for (int tt = 0; tt < 4; ++tt) {
            v4f a = bi;
            a = MFMA16(a0f, bh[tt][0], a);
            a = MFMA16(a1f, bh[tt][1], a);
            acc[m][tt] = a;
        }
    }
    #pragma unroll
    for (int tt = 0; tt < 4; ++tt)
        #pragma unroll
        for (int m = 0; m < 2; ++m) {
            v4h h;
            #pragma unroll
            for (int r = 0; r < 4; ++r) h[r] = (_Float16)fmaxf(acc[m][tt][r], 0.f);
            bh[tt][m] = h;
        }

    v4f acc3[3][4];
    #pragma unroll
    for (int m = 0; m < 3; ++m) {
        const v4f bi = *(const v4f*)(b3s + 16 * m + 4 * g);
        const v4h a0f = *(const v4h*)(w3t + (16 * m + lm) * 36 + 4 * g);
        const v4h a1f = *(const v4h*)(w3t + (16 * m + lm) * 36 + 16 + 4 * g);
        #pragma unroll
        for (int tt = 0; tt < 4; ++tt) {
            v4f a = bi;
            a = MFMA16(a0f, bh[tt][0], a);
            a = MFMA16(a1f, bh[tt][1], a);
            acc3[m][tt] = a;
        }
    }
    v4h pf[4][3];
    #pragma unroll
    for (int tt = 0; tt < 4; ++tt)
        #pragma unroll
        for (int m = 0; m < 3; ++m) {
            v4h h;
            #pragma unroll
            for (int r = 0; r < 4; ++r) h[r] = (_Float16)acc3[m][tt][r];
            pf[tt][m] = h;
        }

    float ep[2][4];
    #pragma unroll
    for (int k = 0; k < 2; ++k) {
        const v4f bi0 = *(const v4f*)(eb0s + k * 32 + 4 * g);
        const v4f bi1 = *(const v4f*)(eb0s + k * 32 + 16 + 4 * g);
        const v4f w10 = *(const v4f*)(ew1s + k * 32 + 4 * g);
        const v4f w11 = *(const v4f*)(ew1s + k * 32 + 16 + 4 * g);
        const _Float16* eb = et + (size_t)k * 1664;
        const v4h e00 = *(const v4h*)(eb + lm * 52 + 4 * g);
        const v4h e01 = *(const v4h*)(eb + lm * 52 + 16 + 4 * g);
        const v4h e02 = *(const v4h*)(eb + lm * 52 + 32 + 4 * g);
        const v4h e10 = *(const v4h*)(eb + (16 + lm) * 52 + 4 * g);
        const v4h e11 = *(const v4h*)(eb + (16 + lm) * 52 + 16 + 4 * g);
        const v4h e12 = *(const v4h*)(eb + (16 + lm) * 52 + 32 + 4 * g);
        #pragma unroll
        for (int tt = 0; tt < 4; ++tt) {
            v4f h0 = bi0, h1 = bi1;
            h0 = MFMA16(e00, pf[tt][0], h0);
            h0 = MFMA16(e01, pf[tt][1], h0);
            h0 = MFMA16(e02, pf[tt][2], h0);
            h1 = MFMA16(e10, pf[tt][0], h1);
            h1 = MFMA16(e11, pf[tt][1], h1);
            h1 = MFMA16(e12, pf[tt][2], h1);
            float p = fmaxf(h0[0], 0.f) * w10[0] + fmaxf(h0[1], 0.f) * w10[1]
                    + fmaxf(h0[2], 0.f) * w10[2] + fmaxf(h0[3], 0.f) * w10[3]
                    + fmaxf(h1[0], 0.f) * w11[0] + fmaxf(h1[1], 0.f) * w11[1]
                    + fmaxf(h1[2], 0.f) * w11[2] + fmaxf(h1[3], 0.f) * w11[3];
            p += __shfl_xor(p, 16);
            p += __shfl_xor(p, 32);
            ep[k][tt] = p + eb1s[k];
        }
    }

    // ---- epilogue: geom via LDS bounce (coalesced), sdfs/offsets by lanes<16 ----
    float* const gw = (float*)(sm + SGEOM) + wv * (16 * 36);
    #pragma unroll
    for (int tt = 0; tt < 4; ++tt) {
        #pragma unroll
        for (int m = 0; m < 3; ++m)
            #pragma unroll
            for (int r = 0; r < 4; ++r) {
                const int o = 16 * m + 4 * g + r;
                if (o >= 1 && o <= 32) gw[lm * 36 + o - 1] = acc3[m][tt][r];
            }
        __syncthreads();
        {
            const int pl = l >> 2, q = l & 3;
            const size_t pid = ptbase + tt * 16 + pl;
            const v4f g0 = *(const v4f*)(gw + pl * 36 + q * 8);
            const v4f g1 = *(const v4f*)(gw + pl * 36 + q * 8 + 4);
            float* og = out + (size_t)NPTS * 6 + pid * 32 + q * 8;
            *reinterpret_cast<v4f*>(og)     = g0;
            *reinterpret_cast<v4f*>(og + 4) = g1;
        }
        if (l < 16) {
            const size_t pid = ptbase + tt * 16 + l;
            const float sdf   = acc3[0][tt][0];
            const float inner = softplus_f(ep[1][tt]);
            const float outer = -softplus_f(ep[0][tt]);
            out[pid * 3 + 0] = sdf + inner + 1e-4f;
            out[pid * 3 + 1] = sdf;
            out[pid * 3 + 2] = sdf + outer - 1e-4f;
            float* oo = out + (size_t)NPTS * 3 + pid * 3;
            oo[0] = inner; oo[1] = 0.f; oo[2] = outer;
        }
        __syncthreads();
    }
}

extern "C" void kernel_launch(void* const* d_in, const int* in_sizes, int n_in,
                              void* d_out, int out_size, void* d_ws, size_t ws_size,
                              hipStream_t stream) {
    const float* points = (const float*)d_in[0];
    const float* table  = (const float*)d_in[1];
    const float* W0  = (const float*)d_in[2];
    const float* b0  = (const float*)d_in[3];
    const float* W1  = (const float*)d_in[4];
    const float* b1  = (const float*)d_in[5];
    const float* W2  = (const float*)d_in[6];
    const float* b2  = (const float*)d_in[7];
    const float* W3  = (const float*)d_in[8];
    const float* b3  = (const float*)d_in[9];
    const float* eW0 = (const float*)d_in[10];
    const float* eb0 = (const float*)d_in[11];
    const float* eW1 = (const float*)d_in[12];
    const float* eb1 = (const float*)d_in[13];
    float* out = (float*)d_out;

    ResParams rp;
    for (int l = 0; l < NLVL; ++l)
        rp.r[l] = (float)floor(16.0 * exp((double)l * log(2048.0 / 16.0) / 23.0));
    (void)in_sizes; (void)n_in; (void)out_size; (void)ws_size;

    uint32_t* enc = (uint32_t*)d_ws;   // 50.3 MB
    hash_gather_pass<<<dim3(NLVL * 512), dim3(256), 0, stream>>>(points, table, enc, rp);
    mlp_mfma<<<dim3(NPTS / 256), dim3(256), 0, stream>>>(
        enc, W0, b0, W1, b1, W2, b2, W3, b3, eW0, eb0, eW1, eb1, out);
}